// Round 22
// baseline (10162.867 us; speedup 1.0000x reference)
//
#include <hip/hip_runtime.h>

// r22 = r20 (best, 4.67ms) + two changes to kill the accvgpr-move tax
// (measured: 512 of 1120 busy cy/slot = moves; VOP2/3 cannot encode AGPR
// src, so each AGPR-banked weight use costs 1 move + 1 FMA):
//  1. amdgpu_waves_per_eu(4,4): RA budget = 128 regs (real residency is
//     4 waves/SIMD anyway: 2 blocks/CU x 8 waves).
//  2. sched_group_barrier (1 DS_READ, 4 VALU) x16 in the hot loops: stops
//     the scheduler hoisting all 16 x-float4 ds_reads (64 live regs) so
//     peak live ~90 < 128 -> weights can stay in ARCH VGPRs, MAC = 2cy.
// Structure unchanged: 512 blocks x 2 rows (chains A,B), 8 waves
// (4 G1: W1-cols, integrate+GEMM1+tanh; 4 G2: W2-rows, GEMM2 partials),
// dual-chain slot pipeline, 1 barrier/slot, stride-5 partials.

#define NB 1024
#define ND 64
#define NH 256
#define NBLK 512     // 2 rows per block
#define NTHR 512     // 8 waves: 4x G1 + 4x G2

// LDS float offsets (1664 floats = 6.5 KB)
#define XBOF(C,W) (((C)<<8) + ((W)<<6))   // xb[2][4][64]  per-chain per-G1-wave x bcast
#define ABOF(C)   (512 + ((C)<<8))        // ab[2][256]    per-chain activations
#define PTOF(C)   (1024 + (C)*320)        // part[2][64*5] stride-5 partials

#define R64(M) M(0) M(1) M(2) M(3) M(4) M(5) M(6) M(7) M(8) M(9) \
  M(10) M(11) M(12) M(13) M(14) M(15) M(16) M(17) M(18) M(19) \
  M(20) M(21) M(22) M(23) M(24) M(25) M(26) M(27) M(28) M(29) \
  M(30) M(31) M(32) M(33) M(34) M(35) M(36) M(37) M(38) M(39) \
  M(40) M(41) M(42) M(43) M(44) M(45) M(46) M(47) M(48) M(49) \
  M(50) M(51) M(52) M(53) M(54) M(55) M(56) M(57) M(58) M(59) \
  M(60) M(61) M(62) M(63)

#define Q16(M) M(0,0,1,2,3) M(1,4,5,6,7) M(2,8,9,10,11) M(3,12,13,14,15) \
  M(4,16,17,18,19) M(5,20,21,22,23) M(6,24,25,26,27) M(7,28,29,30,31) \
  M(8,32,33,34,35) M(9,36,37,38,39) M(10,40,41,42,43) M(11,44,45,46,47) \
  M(12,48,49,50,51) M(13,52,53,54,55) M(14,56,57,58,59) M(15,60,61,62,63)

// (1 DS_READ, 4 VALU) x 16: pre-RA emission order -> low x-read pressure.
#define SHAPE_16x(EXTRA) do { \
    _Pragma("unroll") \
    for (int q_ = 0; q_ < 16; ++q_) { \
        __builtin_amdgcn_sched_group_barrier(0x100, 1, 0); \
        __builtin_amdgcn_sched_group_barrier(0x002, 4, 0); \
    } \
    __builtin_amdgcn_sched_group_barrier(0x002, (EXTRA), 0); \
} while (0)

__device__ __forceinline__ float fast_tanh(float x) {
    float e = __expf(2.0f * x);
    float r = __builtin_amdgcn_rcpf(e + 1.0f);
    return 1.0f - 2.0f * r;
}

// lgkmcnt-only barrier: no vmcnt drain (out stores keep flowing).
#define BSYNC() do {                                             \
    asm volatile("s_waitcnt lgkmcnt(0)" ::: "memory");           \
    __builtin_amdgcn_s_barrier();                                \
    asm volatile("" ::: "memory");                               \
} while (0)

__global__ __launch_bounds__(NTHR)
__attribute__((amdgpu_waves_per_eu(4, 4)))
void node_rk4_kernel(const float* __restrict__ y0,
                     const float* __restrict__ t,
                     const float* W1,
                     const float* b1,
                     const float* W2,
                     const float* b2,
                     float* __restrict__ out,
                     int nsteps)
{
    __shared__ float lds[1664];
    const int tid = threadIdx.x;
    const int w   = tid >> 6;        // wave 0..7
    const int l   = tid & 63;        // lane

    if (w < 4) {
        // ===== G1: integrate + GEMM1 + tanh (chain-alternating) =====
        const int j = (w << 6) + l;            // owned hidden unit
        const float b1l = b1[j];
        const float b2l = b2[l];
        #define DW1(i) float w1_##i;
        R64(DW1)
        #define LW1(i) w1_##i = W1[(i) * NH + j];
        R64(LW1)

        float* xbwA = lds + XBOF(0, w);
        float* xbwB = lds + XBOF(1, w);
        const float4* xqA = (const float4*)xbwA;
        const float4* xqB = (const float4*)xbwB;
        float* abA = lds + ABOF(0) + (w << 6);
        float* abB = lds + ABOF(1) + (w << 6);
        const float* prA = lds + PTOF(0);
        const float* prB = lds + PTOF(1);

        const int row0 = blockIdx.x * 2;
        float yA = y0[(row0 + 0) * ND + l];
        float yB = y0[(row0 + 1) * ND + l];
        float kaA = 0.0f, kaB = 0.0f;
        if (w == 0) {
            out[(size_t)(row0 + 0) * ND + l] = yA;   // step-0 output
            out[(size_t)(row0 + 1) * ND + l] = yB;
        }
        float dt = 0.0f, dt2 = 0.0f, dt6 = 0.0f;
        size_t obase = 0;

#define G1Q(q,i0,i1,i2,i3) { float4 xv_ = xq_[q]; \
    h0_ = fmaf(w1_##i0, xv_.x, h0_); h1_ = fmaf(w1_##i1, xv_.y, h1_); \
    h0_ = fmaf(w1_##i2, xv_.z, h0_); h1_ = fmaf(w1_##i3, xv_.w, h1_); }

// One G1 slot for chain C: finalize stage ST's k (ST=0: init, x=y0),
// RK4-advance x, then GEMM1+tanh -> ab[C]. In-wave x roundtrip via lgkm.
#define G1SLOT(C, CI, ST) do {                                       \
    float x_;                                                        \
    if ((ST) == 0) { x_ = y##C; }                                    \
    else {                                                           \
      const float* pr_ = pr##C + l * 5;                              \
      float kc_ = ((pr_[0] + pr_[1]) + (pr_[2] + pr_[3])) + b2l;     \
      if ((ST)==1)      { ka##C  = kc_;       x_ = fmaf(dt2, kc_, y##C); } \
      else if ((ST)==2) { ka##C += 2.0f*kc_;  x_ = fmaf(dt2, kc_, y##C); } \
      else if ((ST)==3) { ka##C += 2.0f*kc_;  x_ = fmaf(dt,  kc_, y##C); } \
      else { y##C = fmaf(dt6, ka##C + kc_, y##C); x_ = y##C;         \
             if (w == 0) out[obase + (CI) * ND + l] = y##C; }        \
    }                                                                \
    xbw##C[l] = x_;                                                  \
    asm volatile("s_waitcnt lgkmcnt(0)" ::: "memory");               \
    const float4* xq_ = xq##C;                                       \
    float h0_ = b1l, h1_ = 0.0f;                                     \
    Q16(G1Q)                                                         \
    SHAPE_16x(8);                                                    \
    ab##C[l] = fast_tanh(h0_ + h1_);                                 \
} while (0)

        G1SLOT(A, 0, 0); BSYNC();     // slot 0
        G1SLOT(B, 1, 0); BSYNC();     // slot 1
        for (int s = 0; s < nsteps; ++s) {
            dt = t[s + 1] - t[s]; dt2 = 0.5f * dt; dt6 = dt * (1.0f / 6.0f);
            obase = (size_t)(s + 1) * (NB * ND) + (size_t)row0 * ND;
            G1SLOT(A, 0, 1); BSYNC();  G1SLOT(B, 1, 1); BSYNC();
            G1SLOT(A, 0, 2); BSYNC();  G1SLOT(B, 1, 2); BSYNC();
            G1SLOT(A, 0, 3); BSYNC();  G1SLOT(B, 1, 3); BSYNC();
            G1SLOT(A, 0, 4); BSYNC();  G1SLOT(B, 1, 4); BSYNC();
        }
    } else {
        // ===== G2: GEMM2 partials (chain-alternating, stage-agnostic) =====
        const int jj = w - 4;                  // owned j-slice [64jj,64jj+64)
        #define DW2(i) float w2_##i;
        R64(DW2)
        #define LW2(i) w2_##i = W2[((jj << 6) + (i)) * ND + l];
        R64(LW2)

        const float4* aqA = (const float4*)(lds + ABOF(0) + (jj << 6));
        const float4* aqB = (const float4*)(lds + ABOF(1) + (jj << 6));
        float* pwA = lds + PTOF(0);
        float* pwB = lds + PTOF(1);

#define G2Q(q,i0,i1,i2,i3) { float4 av_ = aq_[q]; \
    p0_ = fmaf(w2_##i0, av_.x, p0_); p1_ = fmaf(w2_##i1, av_.y, p1_); \
    p0_ = fmaf(w2_##i2, av_.z, p0_); p1_ = fmaf(w2_##i3, av_.w, p1_); }

#define G2SLOT(C) do {                                               \
    const float4* aq_ = aq##C;                                       \
    float p0_ = 0.0f, p1_ = 0.0f;                                    \
    Q16(G2Q)                                                         \
    SHAPE_16x(2);                                                    \
    pw##C[l * 5 + jj] = p0_ + p1_;   /* stride-5: conflict-free */   \
} while (0)

        BSYNC();                      // slot 0 (idle)
        G2SLOT(A); BSYNC();           // slot 1: A's k1
        for (int s = 0; s < nsteps; ++s) {
            G2SLOT(B); BSYNC();  G2SLOT(A); BSYNC();
            G2SLOT(B); BSYNC();  G2SLOT(A); BSYNC();
            G2SLOT(B); BSYNC();  G2SLOT(A); BSYNC();
            G2SLOT(B); BSYNC();  G2SLOT(A); BSYNC();
        }
    }
}

extern "C" void kernel_launch(void* const* d_in, const int* in_sizes, int n_in,
                              void* d_out, int out_size, void* d_ws, size_t ws_size,
                              hipStream_t stream) {
    const float* y0 = (const float*)d_in[0];
    const float* t  = (const float*)d_in[1];
    const float* W1 = (const float*)d_in[2];
    const float* b1 = (const float*)d_in[3];
    const float* W2 = (const float*)d_in[4];
    const float* b2 = (const float*)d_in[5];
    float* out = (float*)d_out;
    int nsteps = in_sizes[1] - 1;
    hipLaunchKernelGGL(node_rk4_kernel, dim3(NBLK), dim3(NTHR), 0, stream,
                       y0, t, W1, b1, W2, b2, out, nsteps);
}

// Round 23
// 4657.556 us; speedup vs baseline: 2.1820x; 2.1820x over previous
//
#include <hip/hip_runtime.h>

// r23 = r20 (best, 4.67ms) with ONE change: every weight-MAC is inline
// asm v_fmac_f32 with all-"v" constraints. r20's RA split weights 48-arch +
// 64-AGPR (VOP2 can't read AGPR -> 1 v_accvgpr_read per MAC = 45% of busy).
// All-"v" use sites make arch residency the cheapest RA choice (64 weights
// + ~30 working = ~94 < 128-reg budget at launch_bounds(512,4)); if RA
// still banks AGPR it inserts the same moves as today (no regression).
// NO sched pinning, NO waves_per_eu (r22's scratch-spill disaster knobs).
// Structure verbatim r20: 512 blocks x 2 rows (chains A,B), 8 waves
// (4 G1: W1-cols, integrate+GEMM1+tanh; 4 G2: W2-rows, GEMM2 partials),
// dual-chain slot pipeline, 1 lgkm-only barrier/slot, stride-5 partials.

#define NB 1024
#define ND 64
#define NH 256
#define NBLK 512     // 2 rows per block
#define NTHR 512     // 8 waves: 4x G1 + 4x G2

// LDS float offsets (1664 floats = 6.5 KB)
#define XBOF(C,W) (((C)<<8) + ((W)<<6))   // xb[2][4][64]  per-chain per-G1-wave x bcast
#define ABOF(C)   (512 + ((C)<<8))        // ab[2][256]    per-chain activations
#define PTOF(C)   (1024 + (C)*320)        // part[2][64*5] stride-5 partials

#define R64(M) M(0) M(1) M(2) M(3) M(4) M(5) M(6) M(7) M(8) M(9) \
  M(10) M(11) M(12) M(13) M(14) M(15) M(16) M(17) M(18) M(19) \
  M(20) M(21) M(22) M(23) M(24) M(25) M(26) M(27) M(28) M(29) \
  M(30) M(31) M(32) M(33) M(34) M(35) M(36) M(37) M(38) M(39) \
  M(40) M(41) M(42) M(43) M(44) M(45) M(46) M(47) M(48) M(49) \
  M(50) M(51) M(52) M(53) M(54) M(55) M(56) M(57) M(58) M(59) \
  M(60) M(61) M(62) M(63)

#define Q16(M) M(0,0,1,2,3) M(1,4,5,6,7) M(2,8,9,10,11) M(3,12,13,14,15) \
  M(4,16,17,18,19) M(5,20,21,22,23) M(6,24,25,26,27) M(7,28,29,30,31) \
  M(8,32,33,34,35) M(9,36,37,38,39) M(10,40,41,42,43) M(11,44,45,46,47) \
  M(12,48,49,50,51) M(13,52,53,54,55) M(14,56,57,58,59) M(15,60,61,62,63)

// MAC through VOP2 v_fmac with all-arch-VGPR constraints.
#define FMAC(ACC, W, X) \
    asm("v_fmac_f32 %0, %1, %2" : "+v"(ACC) : "v"(W), "v"(X))

__device__ __forceinline__ float fast_tanh(float x) {
    float e = __expf(2.0f * x);
    float r = __builtin_amdgcn_rcpf(e + 1.0f);
    return 1.0f - 2.0f * r;
}

// lgkmcnt-only barrier: no vmcnt drain (out stores keep flowing).
#define BSYNC() do {                                             \
    asm volatile("s_waitcnt lgkmcnt(0)" ::: "memory");           \
    __builtin_amdgcn_s_barrier();                                \
    asm volatile("" ::: "memory");                               \
} while (0)

__global__ __launch_bounds__(NTHR, 4)
void node_rk4_kernel(const float* __restrict__ y0,
                     const float* __restrict__ t,
                     const float* W1,
                     const float* b1,
                     const float* W2,
                     const float* b2,
                     float* __restrict__ out,
                     int nsteps)
{
    __shared__ float lds[1664];
    const int tid = threadIdx.x;
    const int w   = tid >> 6;        // wave 0..7
    const int l   = tid & 63;        // lane

    if (w < 4) {
        // ===== G1: integrate + GEMM1 + tanh (chain-alternating) =====
        const int j = (w << 6) + l;            // owned hidden unit
        const float b1l = b1[j];
        const float b2l = b2[l];
        #define DW1(i) float w1_##i;
        R64(DW1)
        #define LW1(i) w1_##i = W1[(i) * NH + j];
        R64(LW1)

        float* xbwA = lds + XBOF(0, w);
        float* xbwB = lds + XBOF(1, w);
        const float4* xqA = (const float4*)xbwA;
        const float4* xqB = (const float4*)xbwB;
        float* abA = lds + ABOF(0) + (w << 6);
        float* abB = lds + ABOF(1) + (w << 6);
        const float* prA = lds + PTOF(0);
        const float* prB = lds + PTOF(1);

        const int row0 = blockIdx.x * 2;
        float yA = y0[(row0 + 0) * ND + l];
        float yB = y0[(row0 + 1) * ND + l];
        float kaA = 0.0f, kaB = 0.0f;
        if (w == 0) {
            out[(size_t)(row0 + 0) * ND + l] = yA;   // step-0 output
            out[(size_t)(row0 + 1) * ND + l] = yB;
        }
        float dt = 0.0f, dt2 = 0.0f, dt6 = 0.0f;
        size_t obase = 0;

#define G1Q(q,i0,i1,i2,i3) { float4 xv_ = xq_[q]; \
    FMAC(h0_, w1_##i0, xv_.x); FMAC(h1_, w1_##i1, xv_.y); \
    FMAC(h0_, w1_##i2, xv_.z); FMAC(h1_, w1_##i3, xv_.w); }

// One G1 slot for chain C: finalize stage ST's k (ST=0: init, x=y0),
// RK4-advance x, then GEMM1+tanh -> ab[C]. In-wave x roundtrip via lgkm.
#define G1SLOT(C, CI, ST) do {                                       \
    float x_;                                                        \
    if ((ST) == 0) { x_ = y##C; }                                    \
    else {                                                           \
      const float* pr_ = pr##C + l * 5;                              \
      float kc_ = ((pr_[0] + pr_[1]) + (pr_[2] + pr_[3])) + b2l;     \
      if ((ST)==1)      { ka##C  = kc_;       x_ = fmaf(dt2, kc_, y##C); } \
      else if ((ST)==2) { ka##C += 2.0f*kc_;  x_ = fmaf(dt2, kc_, y##C); } \
      else if ((ST)==3) { ka##C += 2.0f*kc_;  x_ = fmaf(dt,  kc_, y##C); } \
      else { y##C = fmaf(dt6, ka##C + kc_, y##C); x_ = y##C;         \
             if (w == 0) out[obase + (CI) * ND + l] = y##C; }        \
    }                                                                \
    xbw##C[l] = x_;                                                  \
    asm volatile("s_waitcnt lgkmcnt(0)" ::: "memory");               \
    const float4* xq_ = xq##C;                                       \
    float h0_ = b1l, h1_ = 0.0f;                                     \
    Q16(G1Q)                                                         \
    ab##C[l] = fast_tanh(h0_ + h1_);                                 \
} while (0)

        G1SLOT(A, 0, 0); BSYNC();     // slot 0
        G1SLOT(B, 1, 0); BSYNC();     // slot 1
        for (int s = 0; s < nsteps; ++s) {
            dt = t[s + 1] - t[s]; dt2 = 0.5f * dt; dt6 = dt * (1.0f / 6.0f);
            obase = (size_t)(s + 1) * (NB * ND) + (size_t)row0 * ND;
            G1SLOT(A, 0, 1); BSYNC();  G1SLOT(B, 1, 1); BSYNC();
            G1SLOT(A, 0, 2); BSYNC();  G1SLOT(B, 1, 2); BSYNC();
            G1SLOT(A, 0, 3); BSYNC();  G1SLOT(B, 1, 3); BSYNC();
            G1SLOT(A, 0, 4); BSYNC();  G1SLOT(B, 1, 4); BSYNC();
        }
    } else {
        // ===== G2: GEMM2 partials (chain-alternating, stage-agnostic) =====
        const int jj = w - 4;                  // owned j-slice [64jj,64jj+64)
        #define DW2(i) float w2_##i;
        R64(DW2)
        #define LW2(i) w2_##i = W2[((jj << 6) + (i)) * ND + l];
        R64(LW2)

        const float4* aqA = (const float4*)(lds + ABOF(0) + (jj << 6));
        const float4* aqB = (const float4*)(lds + ABOF(1) + (jj << 6));
        float* pwA = lds + PTOF(0);
        float* pwB = lds + PTOF(1);

#define G2Q(q,i0,i1,i2,i3) { float4 av_ = aq_[q]; \
    FMAC(p0_, w2_##i0, av_.x); FMAC(p1_, w2_##i1, av_.y); \
    FMAC(p0_, w2_##i2, av_.z); FMAC(p1_, w2_##i3, av_.w); }

#define G2SLOT(C) do {                                               \
    const float4* aq_ = aq##C;                                       \
    float p0_ = 0.0f, p1_ = 0.0f;                                    \
    Q16(G2Q)                                                         \
    pw##C[l * 5 + jj] = p0_ + p1_;   /* stride-5: conflict-free */   \
} while (0)

        BSYNC();                      // slot 0 (idle)
        G2SLOT(A); BSYNC();           // slot 1: A's k1
        for (int s = 0; s < nsteps; ++s) {
            G2SLOT(B); BSYNC();  G2SLOT(A); BSYNC();
            G2SLOT(B); BSYNC();  G2SLOT(A); BSYNC();
            G2SLOT(B); BSYNC();  G2SLOT(A); BSYNC();
            G2SLOT(B); BSYNC();  G2SLOT(A); BSYNC();
        }
    }
}

extern "C" void kernel_launch(void* const* d_in, const int* in_sizes, int n_in,
                              void* d_out, int out_size, void* d_ws, size_t ws_size,
                              hipStream_t stream) {
    const float* y0 = (const float*)d_in[0];
    const float* t  = (const float*)d_in[1];
    const float* W1 = (const float*)d_in[2];
    const float* b1 = (const float*)d_in[3];
    const float* W2 = (const float*)d_in[4];
    const float* b2 = (const float*)d_in[5];
    float* out = (float*)d_out;
    int nsteps = in_sizes[1] - 1;
    hipLaunchKernelGGL(node_rk4_kernel, dim3(NBLK), dim3(NTHR), 0, stream,
                       y0, t, W1, b1, W2, b2, out, nsteps);
}